// Round 1
// baseline (1006.304 us; speedup 1.0000x reference)
//
#include <hip/hip_runtime.h>
#include <hip/hip_bf16.h>

// Problem constants (fixed by reference)
constexpr int NN   = 50000;   // nodes
constexpr int NE   = 800000;  // edges per relation
constexpr int NR   = 3;       // relations
constexpr int DIN  = 96;
constexpr int DH   = 96;
constexpr int DOUT = 64;

// ---------------------------------------------------------------------------
// CSR build: count in-degree per (relation, dst)
// ---------------------------------------------------------------------------
__global__ void count_deg_kernel(const int* __restrict__ dst, int* __restrict__ deg)
{
    int gid = blockIdx.x * blockDim.x + threadIdx.x;
    if (gid >= NR * NE) return;
    int r = gid / NE;                 // compile-time divisor -> magic mul
    int d = dst[gid];
    atomicAdd(&deg[r * NN + d], 1);
}

// Exclusive scan per relation (one 1024-thread block per relation).
// Writes off[r][0..NN] (off[0]=0) and cur[r][n] = off[r][n] (scatter cursors).
__global__ void scan_offsets_kernel(const int* __restrict__ deg,
                                    int* __restrict__ off,
                                    int* __restrict__ cur)
{
    const int r = blockIdx.x;
    const int* d = deg + (size_t)r * NN;
    int* o = off + (size_t)r * (NN + 1);
    int* c = cur + (size_t)r * NN;

    __shared__ int wsum[16];
    __shared__ int s_carry;
    const int tid  = threadIdx.x;        // 0..1023
    const int lane = tid & 63;
    const int w    = tid >> 6;           // wave id 0..15

    if (tid == 0) { s_carry = 0; o[0] = 0; }
    __syncthreads();

    for (int base = 0; base < NN; base += 1024) {
        int i = base + tid;
        int v = (i < NN) ? d[i] : 0;
        int x = v;
        #pragma unroll
        for (int s = 1; s < 64; s <<= 1) {
            int y = __shfl_up(x, s);
            if (lane >= s) x += y;
        }
        if (lane == 63) wsum[w] = x;
        __syncthreads();
        int wpre = 0;
        #pragma unroll
        for (int k = 0; k < 16; ++k) {
            int ws_ = wsum[k];
            if (k < w) wpre += ws_;
        }
        int carry = s_carry;
        int incl  = carry + wpre + x;    // inclusive prefix including carry
        if (i < NN) {
            o[i + 1] = incl;
            c[i]     = incl - v;         // exclusive = off[i]
        }
        __syncthreads();                 // all reads of s_carry/wsum done
        if (tid == 1023) s_carry = incl; // chunk total + old carry
        __syncthreads();
    }
}

// Scatter src ids into dst-sorted CSR using cursors.
__global__ void fill_csr_kernel(const int* __restrict__ src,
                                const int* __restrict__ dst,
                                int* __restrict__ cur,
                                int* __restrict__ csr)
{
    int gid = blockIdx.x * blockDim.x + threadIdx.x;
    if (gid >= NR * NE) return;
    int r = gid / NE;
    int s = src[gid];
    int d = dst[gid];
    int pos = atomicAdd(&cur[r * NN + d], 1);
    csr[(size_t)r * NE + pos] = s;
}

// ---------------------------------------------------------------------------
// Mean-aggregation: one 32-lane group per node; lanes cover 96 dims as
// {t, t+32, t+64}. Row gathers are coalesced 128B loads, L2/L3-resident.
// ---------------------------------------------------------------------------
__global__ __launch_bounds__(256)
void aggregate96_kernel(const float* __restrict__ H,    // [NN][96]
                        const int* __restrict__ csr,    // [NE] src, sorted by dst
                        const int* __restrict__ off,    // [NN+1]
                        float* __restrict__ outb)       // [NN][96]
{
    int g = (blockIdx.x * 256 + threadIdx.x) >> 5;      // node id
    int t = threadIdx.x & 31;
    if (g >= NN) return;
    int s = off[g], e = off[g + 1];
    float a0 = 0.f, a1 = 0.f, a2 = 0.f;
    int i = s;
    int srcv = (i < e) ? csr[i] : 0;
    for (; i < e; ++i) {
        int nxt = (i + 1 < e) ? csr[i + 1] : 0;         // prefetch next index
        const float* row = H + (size_t)srcv * 96;
        a0 += row[t];
        a1 += row[t + 32];
        a2 += row[t + 64];
        srcv = nxt;
    }
    int degv = e - s;
    float inv = 1.0f / (float)(degv > 0 ? degv : 1);
    float* o = outb + (size_t)g * 96;
    o[t]      = a0 * inv;
    o[t + 32] = a1 * inv;
    o[t + 64] = a2 * inv;
}

// ---------------------------------------------------------------------------
// Fused per-relation GEMM + tanh + mean-accumulate:
//   out[n][c] += scale * tanh( A[n]·Ws[:,c] + G[n]·Wn[:,c] + b[c] )
// Block: (NOUT, YR) threads, BM = YR*TM nodes per block.
// A/G tiles in LDS (row-major, reads are wave-broadcast -> conflict-free).
// Weights streamed from global (hot in L1/L2), coalesced across tx.
// ---------------------------------------------------------------------------
template <int NOUT, int YR, int TM>
__global__ __launch_bounds__(NOUT * YR)
void gemm_rel_kernel(const float* __restrict__ A,    // [NN][96]
                     const float* __restrict__ G,    // [NN][96]
                     const float* __restrict__ Ws,   // [96][NOUT]
                     const float* __restrict__ Wn,   // [96][NOUT]
                     const float* __restrict__ bias, // [NOUT]
                     float* __restrict__ outb,       // [NN][NOUT], accumulated
                     float scale)
{
    constexpr int BM = YR * TM;          // 16
    constexpr int NT = NOUT * YR;        // 192 or 256
    __shared__ float xs[BM][96];
    __shared__ float gs[BM][96];

    const int tx = threadIdx.x, ty = threadIdx.y;
    const int tid = ty * NOUT + tx;
    const int n0 = blockIdx.x * BM;

    {
        const float4* A4 = reinterpret_cast<const float4*>(A + (size_t)n0 * 96);
        const float4* G4 = reinterpret_cast<const float4*>(G + (size_t)n0 * 96);
        float4* xs4 = reinterpret_cast<float4*>(&xs[0][0]);
        float4* gs4 = reinterpret_cast<float4*>(&gs[0][0]);
        constexpr int NF4 = BM * 96 / 4; // 384
        for (int i = tid; i < NF4; i += NT) {
            xs4[i] = A4[i];
            gs4[i] = G4[i];
        }
    }
    __syncthreads();

    float acc[TM];
    #pragma unroll
    for (int j = 0; j < TM; ++j) acc[j] = 0.f;
    const int row0 = ty * TM;

    for (int d4 = 0; d4 < 96; d4 += 4) {
        float xr[TM][4], gr[TM][4];
        #pragma unroll
        for (int j = 0; j < TM; ++j) {
            float4 t1 = *reinterpret_cast<const float4*>(&xs[row0 + j][d4]);
            float4 t2 = *reinterpret_cast<const float4*>(&gs[row0 + j][d4]);
            xr[j][0] = t1.x; xr[j][1] = t1.y; xr[j][2] = t1.z; xr[j][3] = t1.w;
            gr[j][0] = t2.x; gr[j][1] = t2.y; gr[j][2] = t2.z; gr[j][3] = t2.w;
        }
        #pragma unroll
        for (int dd = 0; dd < 4; ++dd) {
            float wsv = Ws[(d4 + dd) * NOUT + tx];
            float wnv = Wn[(d4 + dd) * NOUT + tx];
            #pragma unroll
            for (int j = 0; j < TM; ++j)
                acc[j] += xr[j][dd] * wsv + gr[j][dd] * wnv;
        }
    }

    const float bb = bias[tx];
    #pragma unroll
    for (int j = 0; j < TM; ++j) {
        const int n = n0 + row0 + j;
        outb[(size_t)n * NOUT + tx] += scale * tanhf(acc[j] + bb);
    }
}

// ---------------------------------------------------------------------------
extern "C" void kernel_launch(void* const* d_in, const int* in_sizes, int n_in,
                              void* d_out, int out_size, void* d_ws, size_t ws_size,
                              hipStream_t stream)
{
    const float* x   = (const float*)d_in[0];
    const int*   src = (const int*)d_in[1];
    const int*   dst = (const int*)d_in[2];
    const float* Ws1 = (const float*)d_in[3];
    const float* Wn1 = (const float*)d_in[4];
    const float* b1  = (const float*)d_in[5];
    const float* Ws2 = (const float*)d_in[6];
    const float* Wn2 = (const float*)d_in[7];
    const float* b2  = (const float*)d_in[8];
    float* out = (float*)d_out;

    // Workspace layout (256B-aligned slices), ~50 MB total.
    char* ws = (char*)d_ws;
    size_t o = 0;
    auto alloc = [&](size_t bytes) {
        size_t p = o;
        o += (bytes + 255) & ~(size_t)255;
        return p;
    };
    int*   deg = (int*)(ws + alloc((size_t)NR * NN * 4));
    int*   off = (int*)(ws + alloc((size_t)NR * (NN + 1) * 4));
    int*   cur = (int*)(ws + alloc((size_t)NR * NN * 4));
    int*   csr = (int*)(ws + alloc((size_t)NR * NE * 4));
    float* agg = (float*)(ws + alloc((size_t)NN * 96 * 4));
    float* h1  = (float*)(ws + alloc((size_t)NN * 96 * 4));

    // --- CSR build (once; shared by both layers) ---
    hipMemsetAsync(deg, 0, (size_t)NR * NN * 4, stream);
    count_deg_kernel<<<(NR * NE + 255) / 256, 256, 0, stream>>>(dst, deg);
    scan_offsets_kernel<<<NR, 1024, 0, stream>>>(deg, off, cur);
    fill_csr_kernel<<<(NR * NE + 255) / 256, 256, 0, stream>>>(src, dst, cur, csr);

    const float scale = 1.0f / (float)NR;

    // --- Layer 1: h1 = mean_r tanh(x@Ws1_r + agg_r(x)@Wn1_r + b1_r) ---
    hipMemsetAsync(h1, 0, (size_t)NN * 96 * 4, stream);
    for (int r = 0; r < NR; ++r) {
        aggregate96_kernel<<<(NN + 7) / 8, 256, 0, stream>>>(
            x, csr + (size_t)r * NE, off + (size_t)r * (NN + 1), agg);
        gemm_rel_kernel<DH, 2, 8><<<NN / 16, dim3(DH, 2), 0, stream>>>(
            x, agg,
            Ws1 + (size_t)r * DIN * DH,
            Wn1 + (size_t)r * DIN * DH,
            b1 + (size_t)r * DH,
            h1, scale);
    }

    // --- Layer 2: out = mean_r tanh(h1@Ws2_r + agg_r(h1)@Wn2_r + b2_r) ---
    hipMemsetAsync(out, 0, (size_t)NN * DOUT * 4, stream);
    for (int r = 0; r < NR; ++r) {
        aggregate96_kernel<<<(NN + 7) / 8, 256, 0, stream>>>(
            h1, csr + (size_t)r * NE, off + (size_t)r * (NN + 1), agg);
        gemm_rel_kernel<DOUT, 4, 4><<<NN / 16, dim3(DOUT, 4), 0, stream>>>(
            h1, agg,
            Ws2 + (size_t)r * DH * DOUT,
            Wn2 + (size_t)r * DH * DOUT,
            b2 + (size_t)r * DOUT,
            out, scale);
    }
}

// Round 2
// 633.531 us; speedup vs baseline: 1.5884x; 1.5884x over previous
//
#include <hip/hip_runtime.h>
#include <hip/hip_bf16.h>

// Problem constants (fixed by reference)
constexpr int NN   = 50000;   // nodes
constexpr int NE   = 800000;  // edges per relation
constexpr int NR   = 3;       // relations
constexpr int DIN  = 96;
constexpr int DH   = 96;
constexpr int DOUT = 64;
constexpr int NBLK = (NN + 1023) / 1024;   // 49 scan blocks per relation

// ---- bf16 helpers (RNE) ----------------------------------------------------
__device__ __forceinline__ unsigned short f2b(float f) {
    unsigned int u = __float_as_uint(f);
    u += 0x7fffu + ((u >> 16) & 1u);       // round-to-nearest-even
    return (unsigned short)(u >> 16);
}
__device__ __forceinline__ float blo(unsigned int u) { return __uint_as_float(u << 16); }
__device__ __forceinline__ float bhi(unsigned int u) { return __uint_as_float(u & 0xffff0000u); }
__device__ __forceinline__ unsigned int pack2(float lo, float hi) {
    return (unsigned int)f2b(lo) | ((unsigned int)f2b(hi) << 16);
}

// ---------------------------------------------------------------------------
// CSR build, pass 1: count in-degree AND capture each edge's rank (the old
// atomic value) so the fill pass needs no atomics.
// ---------------------------------------------------------------------------
__global__ void count_rank_kernel(const int* __restrict__ dst,
                                  int* __restrict__ deg,
                                  int* __restrict__ rank)
{
    int gid = blockIdx.x * blockDim.x + threadIdx.x;
    if (gid >= NR * NE) return;
    int r = gid / NE;
    int d = dst[gid];
    rank[gid] = atomicAdd(&deg[r * NN + d], 1);
}

// ---- 3-phase exclusive scan of deg -> off (per relation) -------------------
__global__ __launch_bounds__(1024)
void scan_partial_kernel(const int* __restrict__ deg, int* __restrict__ bsum)
{
    int r = blockIdx.x / NBLK, b = blockIdx.x % NBLK;
    int i = b * 1024 + threadIdx.x;
    int v = (i < NN) ? deg[(size_t)r * NN + i] : 0;
    #pragma unroll
    for (int s = 32; s; s >>= 1) v += __shfl_xor(v, s);
    __shared__ int ws[16];
    int w = threadIdx.x >> 6;
    if ((threadIdx.x & 63) == 0) ws[w] = v;
    __syncthreads();
    if (threadIdx.x == 0) {
        int t = 0;
        #pragma unroll
        for (int k = 0; k < 16; ++k) t += ws[k];
        bsum[blockIdx.x] = t;
    }
}

__global__ void scan_bsum_kernel(int* __restrict__ bsum)
{
    int r = threadIdx.x;
    if (r >= NR) return;
    int acc = 0;
    for (int b = 0; b < NBLK; ++b) {
        int v = bsum[r * NBLK + b];
        bsum[r * NBLK + b] = acc;
        acc += v;
    }
}

__global__ __launch_bounds__(1024)
void scan_final_kernel(const int* __restrict__ deg,
                       const int* __restrict__ bsum,
                       int* __restrict__ off)
{
    int r = blockIdx.x / NBLK, b = blockIdx.x % NBLK;
    int i = b * 1024 + threadIdx.x;
    int v = (i < NN) ? deg[(size_t)r * NN + i] : 0;
    int x = v;
    const int lane = threadIdx.x & 63;
    #pragma unroll
    for (int s = 1; s < 64; s <<= 1) {
        int y = __shfl_up(x, s);
        if (lane >= s) x += y;
    }
    __shared__ int wsum[16];
    int w = threadIdx.x >> 6;
    if (lane == 63) wsum[w] = x;
    __syncthreads();
    int pre = bsum[blockIdx.x];
    #pragma unroll
    for (int k = 0; k < 16; ++k) {
        int ws_ = wsum[k];
        if (k < w) pre += ws_;
    }
    int incl = pre + x;
    int* o = off + (size_t)r * (NN + 1);
    if (i < NN) o[i] = incl - v;
    if (i == NN - 1) o[NN] = incl;
}

// CSR fill: pure scattered write, no atomics.
__global__ void fill_csr_kernel(const int* __restrict__ src,
                                const int* __restrict__ dst,
                                const int* __restrict__ rank,
                                const int* __restrict__ off,
                                int* __restrict__ csr)
{
    int gid = blockIdx.x * blockDim.x + threadIdx.x;
    if (gid >= NR * NE) return;
    int r = gid / NE;
    int d = dst[gid];
    int pos = off[(size_t)r * (NN + 1) + d] + rank[gid];
    csr[(size_t)r * NE + pos] = src[gid];
}

// ---- f32 -> bf16 bulk convert (8 elems/thread) -----------------------------
__global__ void f32_to_bf16_kernel(const float* __restrict__ in,
                                   unsigned short* __restrict__ out, int n)
{
    int i = (blockIdx.x * 256 + threadIdx.x) * 8;
    if (i >= n) return;
    float4 a = *reinterpret_cast<const float4*>(in + i);
    float4 b = *reinterpret_cast<const float4*>(in + i + 4);
    uint4 o;
    o.x = pack2(a.x, a.y);
    o.y = pack2(a.z, a.w);
    o.z = pack2(b.x, b.y);
    o.w = pack2(b.z, b.w);
    *reinterpret_cast<uint4*>(out + i) = o;
}

// ---------------------------------------------------------------------------
// Mean-aggregation over bf16 rows. 16 lanes per node; lane t reads dwords
// {t, t+16, t+32} of each 48-dword (96 bf16) row => three 64B cache lines
// per row, fully coalesced. fp32 accumulate, bf16 output.
// ---------------------------------------------------------------------------
__global__ __launch_bounds__(256)
void aggregate_bf16_kernel(const unsigned int* __restrict__ Hb,   // [NN][48] dwords
                           const int* __restrict__ csr,
                           const int* __restrict__ off,
                           unsigned int* __restrict__ outb)       // [NN][48]
{
    int g = (blockIdx.x * 256 + threadIdx.x) >> 4;
    int t = threadIdx.x & 15;
    if (g >= NN) return;
    int s = off[g], e = off[g + 1];
    float a0 = 0.f, a1 = 0.f, a2 = 0.f, a3 = 0.f, a4 = 0.f, a5 = 0.f;
    int i = s;
    for (; i + 1 < e; i += 2) {
        int s0 = csr[i], s1 = csr[i + 1];
        const unsigned int* r0 = Hb + (size_t)s0 * 48;
        const unsigned int* r1 = Hb + (size_t)s1 * 48;
        unsigned int u0 = r0[t], u1 = r0[t + 16], u2 = r0[t + 32];
        unsigned int v0 = r1[t], v1 = r1[t + 16], v2 = r1[t + 32];
        a0 += blo(u0) + blo(v0); a1 += bhi(u0) + bhi(v0);
        a2 += blo(u1) + blo(v1); a3 += bhi(u1) + bhi(v1);
        a4 += blo(u2) + blo(v2); a5 += bhi(u2) + bhi(v2);
    }
    if (i < e) {
        const unsigned int* r0 = Hb + (size_t)csr[i] * 48;
        unsigned int u0 = r0[t], u1 = r0[t + 16], u2 = r0[t + 32];
        a0 += blo(u0); a1 += bhi(u0);
        a2 += blo(u1); a3 += bhi(u1);
        a4 += blo(u2); a5 += bhi(u2);
    }
    int degv = e - s;
    float inv = 1.0f / (float)(degv > 0 ? degv : 1);
    unsigned int* o = outb + (size_t)g * 48;
    o[t]      = pack2(a0 * inv, a1 * inv);
    o[t + 16] = pack2(a2 * inv, a3 * inv);
    o[t + 32] = pack2(a4 * inv, a5 * inv);
}

// ---------------------------------------------------------------------------
// Fused per-relation GEMM + tanh + mean-accumulate (bf16 A/G, fp32 math):
//   out[n][c] += scale * tanh( A[n]·Ws[:,c] + G[n]·Wn[:,c] + b[c] )
// Optionally also emits the running sum as bf16 (for the last relation of
// layer 1, so layer 2 can consume h1 in bf16 with no extra pass).
// ---------------------------------------------------------------------------
template <int NOUT, int YR, int TM, bool WRITE_B16>
__global__ __launch_bounds__(NOUT * YR)
void gemm_rel_kernel(const unsigned short* __restrict__ A,   // [NN][96] bf16
                     const unsigned short* __restrict__ G,   // [NN][96] bf16
                     const float* __restrict__ Ws,           // [96][NOUT]
                     const float* __restrict__ Wn,           // [96][NOUT]
                     const float* __restrict__ bias,         // [NOUT]
                     float* __restrict__ outb,               // [NN][NOUT] accum
                     unsigned short* __restrict__ outb16,    // [NN][NOUT] bf16
                     float scale)
{
    constexpr int BM = YR * TM;          // 16
    constexpr int NT = NOUT * YR;        // 192 or 256
    __shared__ float xs[BM][96];
    __shared__ float gs[BM][96];

    const int tx = threadIdx.x, ty = threadIdx.y;
    const int tid = ty * NOUT + tx;
    const int n0 = blockIdx.x * BM;

    {
        const unsigned int* A32 = reinterpret_cast<const unsigned int*>(A + (size_t)n0 * 96);
        const unsigned int* G32 = reinterpret_cast<const unsigned int*>(G + (size_t)n0 * 96);
        float* xsf = &xs[0][0];
        float* gsf = &gs[0][0];
        constexpr int ND = BM * 48;      // 768 dwords per matrix
        for (int i = tid; i < ND; i += NT) {
            unsigned int u = A32[i];
            xsf[2 * i]     = blo(u);
            xsf[2 * i + 1] = bhi(u);
            unsigned int v = G32[i];
            gsf[2 * i]     = blo(v);
            gsf[2 * i + 1] = bhi(v);
        }
    }
    __syncthreads();

    float acc[TM];
    #pragma unroll
    for (int j = 0; j < TM; ++j) acc[j] = 0.f;
    const int row0 = ty * TM;

    for (int d4 = 0; d4 < 96; d4 += 4) {
        float xr[TM][4], gr[TM][4];
        #pragma unroll
        for (int j = 0; j < TM; ++j) {
            float4 t1 = *reinterpret_cast<const float4*>(&xs[row0 + j][d4]);
            float4 t2 = *reinterpret_cast<const float4*>(&gs[row0 + j][d4]);
            xr[j][0] = t1.x; xr[j][1] = t1.y; xr[j][2] = t1.z; xr[j][3] = t1.w;
            gr[j][0] = t2.x; gr[j][1] = t2.y; gr[j][2] = t2.z; gr[j][3] = t2.w;
        }
        #pragma unroll
        for (int dd = 0; dd < 4; ++dd) {
            float wsv = Ws[(d4 + dd) * NOUT + tx];
            float wnv = Wn[(d4 + dd) * NOUT + tx];
            #pragma unroll
            for (int j = 0; j < TM; ++j)
                acc[j] += xr[j][dd] * wsv + gr[j][dd] * wnv;
        }
    }

    const float bb = bias[tx];
    #pragma unroll
    for (int j = 0; j < TM; ++j) {
        const int n = n0 + row0 + j;
        float v = outb[(size_t)n * NOUT + tx] + scale * tanhf(acc[j] + bb);
        outb[(size_t)n * NOUT + tx] = v;
        if (WRITE_B16) outb16[(size_t)n * NOUT + tx] = f2b(v);
    }
}

// ---------------------------------------------------------------------------
extern "C" void kernel_launch(void* const* d_in, const int* in_sizes, int n_in,
                              void* d_out, int out_size, void* d_ws, size_t ws_size,
                              hipStream_t stream)
{
    const float* x   = (const float*)d_in[0];
    const int*   src = (const int*)d_in[1];
    const int*   dst = (const int*)d_in[2];
    const float* Ws1 = (const float*)d_in[3];
    const float* Wn1 = (const float*)d_in[4];
    const float* b1  = (const float*)d_in[5];
    const float* Ws2 = (const float*)d_in[6];
    const float* Wn2 = (const float*)d_in[7];
    const float* b2  = (const float*)d_in[8];
    float* out = (float*)d_out;

    // Workspace layout (256B-aligned), ~59 MB total.
    char* ws = (char*)d_ws;
    size_t o = 0;
    auto alloc = [&](size_t bytes) {
        size_t p = o;
        o += (bytes + 255) & ~(size_t)255;
        return p;
    };
    int* deg  = (int*)(ws + alloc((size_t)NR * NN * 4));            // 0.6 MB
    int* off  = (int*)(ws + alloc((size_t)NR * (NN + 1) * 4));      // 0.6 MB
    int* bsum = (int*)(ws + alloc((size_t)NR * NBLK * 4));          // tiny
    int* csr  = (int*)(ws + alloc((size_t)NR * NE * 4));            // 9.6 MB
    unsigned int* aggb = (unsigned int*)(ws + alloc((size_t)NN * 48 * 4));   // 9.6 MB
    float* h1 = (float*)(ws + alloc((size_t)NN * 96 * 4));          // 19.2 MB
    unsigned short* h1b = (unsigned short*)(ws + alloc((size_t)NN * 96 * 2)); // 9.6 MB
    // rank (CSR build) and xb (x in bf16) are disjoint in time -> share space
    size_t union_off = alloc((size_t)NR * NE * 4);                  // 9.6 MB
    int* rank = (int*)(ws + union_off);
    unsigned short* xb = (unsigned short*)(ws + union_off);

    // --- CSR build (rank-fused: fill pass has no atomics) ---
    hipMemsetAsync(deg, 0, (size_t)NR * NN * 4, stream);
    count_rank_kernel<<<(NR * NE + 255) / 256, 256, 0, stream>>>(dst, deg, rank);
    scan_partial_kernel<<<NR * NBLK, 1024, 0, stream>>>(deg, bsum);
    scan_bsum_kernel<<<1, 64, 0, stream>>>(bsum);
    scan_final_kernel<<<NR * NBLK, 1024, 0, stream>>>(deg, bsum, off);
    fill_csr_kernel<<<(NR * NE + 255) / 256, 256, 0, stream>>>(src, dst, rank, off, csr);

    // --- x -> bf16 (overwrites rank; CSR build is complete by now) ---
    f32_to_bf16_kernel<<<(NN * 96 / 8 + 255) / 256, 256, 0, stream>>>(x, xb, NN * 96);

    const float scale = 1.0f / (float)NR;

    // --- Layer 1: h1 = mean_r tanh(x@Ws1_r + agg_r(x)@Wn1_r + b1_r) ---
    hipMemsetAsync(h1, 0, (size_t)NN * 96 * 4, stream);
    for (int r = 0; r < NR; ++r) {
        aggregate_bf16_kernel<<<(NN * 16 + 255) / 256, 256, 0, stream>>>(
            (const unsigned int*)xb, csr + (size_t)r * NE, off + (size_t)r * (NN + 1), aggb);
        if (r == NR - 1)
            gemm_rel_kernel<DH, 2, 8, true><<<NN / 16, dim3(DH, 2), 0, stream>>>(
                xb, (const unsigned short*)aggb,
                Ws1 + (size_t)r * DIN * DH, Wn1 + (size_t)r * DIN * DH,
                b1 + (size_t)r * DH, h1, h1b, scale);
        else
            gemm_rel_kernel<DH, 2, 8, false><<<NN / 16, dim3(DH, 2), 0, stream>>>(
                xb, (const unsigned short*)aggb,
                Ws1 + (size_t)r * DIN * DH, Wn1 + (size_t)r * DIN * DH,
                b1 + (size_t)r * DH, h1, h1b, scale);
    }

    // --- Layer 2: out = mean_r tanh(h1@Ws2_r + agg_r(h1)@Wn2_r + b2_r) ---
    hipMemsetAsync(out, 0, (size_t)NN * DOUT * 4, stream);
    for (int r = 0; r < NR; ++r) {
        aggregate_bf16_kernel<<<(NN * 16 + 255) / 256, 256, 0, stream>>>(
            (const unsigned int*)h1b, csr + (size_t)r * NE, off + (size_t)r * (NN + 1), aggb);
        gemm_rel_kernel<DOUT, 4, 4, false><<<NN / 16, dim3(DOUT, 4), 0, stream>>>(
            h1b, (const unsigned short*)aggb,
            Ws2 + (size_t)r * DH * DOUT, Wn2 + (size_t)r * DH * DOUT,
            b2 + (size_t)r * DOUT, out, (unsigned short*)nullptr, scale);
    }
}